// Round 12
// baseline (284.603 us; speedup 1.0000x reference)
//
#include <hip/hip_runtime.h>
#include <stdint.h>

typedef unsigned short ushort_t;
typedef __bf16 bf16x8 __attribute__((ext_vector_type(8)));
typedef float f32x4 __attribute__((ext_vector_type(4)));
typedef unsigned short ushort8 __attribute__((ext_vector_type(8)));
typedef unsigned short ushort4_t __attribute__((ext_vector_type(4)));

#define DEV static __device__ __forceinline__

DEV unsigned short f2bf(float f) {
    union { float f; unsigned int i; } v; v.f = f;
    unsigned int u = v.i;
    return (unsigned short)((u + 0x7fffu + ((u >> 16) & 1u)) >> 16);
}
DEV float bf2f(unsigned short u) {
    union { unsigned int i; float f; } v; v.i = ((unsigned int)u) << 16; return v.f;
}
DEV bf16x8 u2b(ushort8 u) { union { ushort8 u; bf16x8 b; } x; x.u = u; return x.b; }

// ---------------------------------------------------------------------------
// prep: w1->bf16, w2->bf16, points2->bf16, zero BN stat accumulators.
// ---------------------------------------------------------------------------
__global__ __launch_bounds__(256) void prep_kernel(
    const float* __restrict__ w1, const float* __restrict__ w2,
    const float* __restrict__ points2,
    ushort_t* __restrict__ w1b, ushort_t* __restrict__ w2b,
    ushort_t* __restrict__ p2b, float* __restrict__ stats)
{
    const int bx = blockIdx.x;
    if (bx < 512) {
        int i = bx * 256 + threadIdx.x;
        w1b[i] = f2bf(w1[i]);
    } else if (bx < 768) {
        int i = (bx - 512) * 256 + threadIdx.x;
        w2b[i] = f2bf(w2[i]);
    } else if (bx < 4864) {
        int i = ((bx - 768) * 256 + threadIdx.x) * 4;
        float4 v = *(const float4*)(points2 + i);
        ushort4_t o;
        o[0] = f2bf(v.x); o[1] = f2bf(v.y); o[2] = f2bf(v.z); o[3] = f2bf(v.w);
        *(ushort4_t*)(p2b + i) = o;
    } else {
        int i = threadIdx.x * 8;
        *(float4*)(stats + i)     = make_float4(0.f, 0.f, 0.f, 0.f);
        *(float4*)(stats + i + 4) = make_float4(0.f, 0.f, 0.f, 0.f);
    }
}

// ---------------------------------------------------------------------------
// 3-NN: 8-way candidate split. Stable ties.
// ---------------------------------------------------------------------------
__global__ __launch_bounds__(256) void knn_kernel(
    const float* __restrict__ xyz1, const float* __restrict__ xyz2,
    int* __restrict__ idx_out, float* __restrict__ w_out)
{
    __shared__ float4 P[1024];
    __shared__ float mD[24][32];
    __shared__ int   mI[24][32];
    const int b = blockIdx.y;
    const int tid = threadIdx.x;
    for (int s = tid; s < 1024; s += 256) {
        const float* p = xyz2 + ((size_t)b * 1024 + s) * 3;
        float x = p[0], y = p[1], z = p[2];
        float pp = __fadd_rn(__fadd_rn(__fmul_rn(x, x), __fmul_rn(y, y)), __fmul_rn(z, z));
        P[s] = make_float4(x, y, z, pp);
    }
    __syncthreads();
    const int ql = tid & 31;
    const int chunk = tid >> 5;
    const int n = blockIdx.x * 32 + ql;
    const float* q = xyz1 + ((size_t)b * 4096 + n) * 3;
    float qx = q[0], qy = q[1], qz = q[2];
    float qq = __fadd_rn(__fadd_rn(__fmul_rn(qx, qx), __fmul_rn(qy, qy)), __fmul_rn(qz, qz));
    float d0 = 1e30f, d1 = 1e30f, d2 = 1e30f;
    int i0 = 0, i1 = 0, i2 = 0;
    const int s0 = chunk * 128;
#pragma unroll 4
    for (int s = s0; s < s0 + 128; ++s) {
        float4 p = P[s];
        float dot = __fadd_rn(__fadd_rn(__fmul_rn(qx, p.x), __fmul_rn(qy, p.y)), __fmul_rn(qz, p.z));
        float d = __fsub_rn(__fadd_rn(qq, p.w), __fmul_rn(2.0f, dot));
        if (d < d2) {
            if (d < d1) {
                d2 = d1; i2 = i1;
                if (d < d0) { d1 = d0; i1 = i0; d0 = d; i0 = s; }
                else        { d1 = d;  i1 = s; }
            } else { d2 = d; i2 = s; }
        }
    }
    mD[chunk * 3 + 0][ql] = d0; mI[chunk * 3 + 0][ql] = i0;
    mD[chunk * 3 + 1][ql] = d1; mI[chunk * 3 + 1][ql] = i1;
    mD[chunk * 3 + 2][ql] = d2; mI[chunk * 3 + 2][ql] = i2;
    __syncthreads();
    if (tid < 32) {
        float e0 = 1e30f, e1 = 1e30f, e2 = 1e30f;
        int j0 = 0, j1 = 0, j2 = 0;
#pragma unroll
        for (int c = 0; c < 24; ++c) {
            float d = mD[c][ql]; int i = mI[c][ql];
            if (d < e2) {
                if (d < e1) {
                    e2 = e1; j2 = j1;
                    if (d < e0) { e1 = e0; j1 = j0; e0 = d; j0 = i; }
                    else        { e1 = d;  j1 = i; }
                } else { e2 = d; j2 = i; }
            }
        }
        float r0 = 1.0f / (e0 + 1e-8f);
        float r1 = 1.0f / (e1 + 1e-8f);
        float r2 = 1.0f / (e2 + 1e-8f);
        float rs = __fadd_rn(__fadd_rn(r0, r1), r2);
        size_t o = ((size_t)b * 4096 + n) * 3;
        idx_out[o + 0] = j0; idx_out[o + 1] = j1; idx_out[o + 2] = j2;
        w_out[o + 0] = r0 / rs; w_out[o + 1] = r1 / rs; w_out[o + 2] = r2 / rs;
    }
}

DEV void cvt8(const float4& u0, const float4& u1, ushort8& hv) {
    hv[0] = f2bf(u0.x); hv[1] = f2bf(u0.y); hv[2] = f2bf(u0.z); hv[3] = f2bf(u0.w);
    hv[4] = f2bf(u1.x); hv[5] = f2bf(u1.y); hv[6] = f2bf(u1.z); hv[7] = f2bf(u1.w);
}

// ---------------------------------------------------------------------------
// GEMM1 v13 = v11 + aPre hoist MADE TO FIT: B single-buffered (bfb 64->32
// regs) frees the budget v12 lacked. Registers: acc 32 + bfb 32 + aPre 32 +
// afb 16 + misc ~12 = ~124 <= 128 (4 waves/SIMD). The interp half of the
// K-loop now feeds MFMA straight from registers (chain broken — R9/R10
// diagnosis); B's read-only-LDS latency per step is covered by cross-wave
// TLP (m114 co-scheduling; compiler emits fine lgkmcnt). fp32 half keeps
// 2-deep direct-load dbuf. XCD swizzle retained (FETCH 41 MB). Spill
// detector: WRITE_SIZE >> 35 MB (v12 showed 142 MB; VGPR_Count counter
// reads 64 either way and is NOT trustworthy).
// ---------------------------------------------------------------------------
__global__ __launch_bounds__(1024, 4) void gemm1_kernel(
    const float* __restrict__ p1, const ushort_t* __restrict__ p2b,
    const int* __restrict__ idx, const float* __restrict__ wgt,
    const ushort_t* __restrict__ w1b, ushort_t* __restrict__ y,
    float* __restrict__ sums, float* __restrict__ sqs)
{
    __shared__ __align__(16) char smem[133120];   // Bs: 128 x 520 ushort
    ushort_t* Bs = (ushort_t*)smem;
    const int tid = threadIdx.x;
    const int wave = tid >> 6, lane = tid & 63;
    const int frl = lane & 15, fq = lane >> 4;
    // batch-affine XCD swizzle: bid -> (panel, nb)
    const int bid = blockIdx.x;
    const int xcd = bid & 7;
    const int j6 = bid >> 3;                 // 0..63
    const int batch = xcd * 2 + (j6 >> 5);   // 0..15
    const int wblk = j6 & 31;                // 0..31 within batch
    const int panel = batch * 16 + (wblk >> 1), nb = wblk & 1;
    const int m0 = panel * 256;

    const int row0 = m0 + wave * 16 + frl;   // fixed row per thread
    // 3-NN indices/weights + gather bases for this row (once)
    const size_t io = (size_t)row0 * 3;
    const float iw0 = wgt[io], iw1 = wgt[io + 1], iw2 = wgt[io + 2];
    const ushort_t* pb = p2b + (size_t)(row0 >> 12) * (1024 * 256);
    const ushort_t* gp0 = pb + (size_t)idx[io] * 256 + fq * 8;
    const ushort_t* gp1 = pb + (size_t)idx[io + 1] * 256 + fq * 8;
    const ushort_t* gp2 = pb + (size_t)idx[io + 2] * 256 + fq * 8;

    // PROLOGUE: all 8 interp A-frags into registers. Gather latency overlaps
    // the B-staging below; convert VALU overlaps across waves.
    bf16x8 aPre[8];
#pragma unroll
    for (int kc = 0; kc < 8; ++kc) {
        ushort8 ga = *(const ushort8*)(gp0 + kc * 32);
        ushort8 gb = *(const ushort8*)(gp1 + kc * 32);
        ushort8 gc = *(const ushort8*)(gp2 + kc * 32);
        ushort8 hv;
#pragma unroll
        for (int e = 0; e < 8; ++e) {
            float av = __fmul_rn(iw0, bf2f(ga[e]));
            av = fmaf(iw1, bf2f(gb[e]), av);
            av = fmaf(iw2, bf2f(gc[e]), av);
            hv[e] = f2bf(av);
        }
        aPre[kc] = u2b(hv);
    }

    // stage B once: 8 threads per col, 8 x 8-elem chunks each
    {
        const int c = tid >> 3, qq = tid & 7;
        const ushort_t* src = w1b + (size_t)(nb * 128 + c) * 512;
        ushort_t* dst = Bs + c * 520;
#pragma unroll
        for (int s = 0; s < 8; ++s) {
            int off = qq * 8 + s * 64;
            *(ushort8*)(dst + off) = *(const ushort8*)(src + off);
        }
    }

    f32x4 acc[8];
#pragma unroll
    for (int j = 0; j < 8; ++j) acc[j] = f32x4{0.0f, 0.0f, 0.0f, 0.0f};

    __syncthreads();   // only barrier before K-loop

    bf16x8 afb[2];     // fp32-half dbuf only
    bf16x8 bfb[8];     // single-buffered B (freed 32 regs for aPre)

#define G1_LOADA32(buf, kc) {                                                      \
    const float4* g = (const float4*)(p1 + (size_t)row0 * 256                      \
                                      + (kc) * 32 + fq * 8);                       \
    float4 u0 = g[0], u1 = g[1];                                                   \
    ushort8 hv; cvt8(u0, u1, hv);                                                  \
    buf = u2b(hv); }
#define G1_LOADB(buf, kc) { _Pragma("unroll")                                      \
    for (int j = 0; j < 8; ++j)                                                    \
        buf[j] = *(const bf16x8*)(Bs + (j * 16 + frl) * 520 + (kc) * 32 + fq * 8); }

    G1_LOADA32(afb[0], 0);
#pragma unroll
    for (int kc = 0; kc < 16; ++kc) {
        G1_LOADB(bfb, kc);                         // LDS reads for this step
        if (kc < 7) G1_LOADA32(afb[(kc + 1) & 1], kc + 1);
        const bf16x8 av = (kc < 8) ? afb[kc & 1] : aPre[kc - 8];
#pragma unroll
        for (int j = 0; j < 8; ++j)
            acc[j] = __builtin_amdgcn_mfma_f32_16x16x32_bf16(av, bfb[j], acc[j], 0, 0, 0);
    }

    // epilogue: y1 store + per-col stats
    float ps[8], pq[8];
#pragma unroll
    for (int j = 0; j < 8; ++j) {
        const int colg = nb * 128 + j * 16 + frl;
        float s = 0.f, q = 0.f;
#pragma unroll
        for (int rr = 0; rr < 4; ++rr) {
            ushort_t hb = f2bf(acc[j][rr]);
            float v = bf2f(hb);
            y[(size_t)(m0 + wave * 16 + fq * 4 + rr) * 256 + colg] = hb;
            s += v; q = fmaf(v, v, q);
        }
        s += __shfl_xor(s, 16); s += __shfl_xor(s, 32);
        q += __shfl_xor(q, 16); q += __shfl_xor(q, 32);
        ps[j] = s; pq[j] = q;
    }
    __syncthreads();                      // Bs now dead -> reuse as scratch
    float* scrS = (float*)smem;           // [16][128]
    float* scrQ = (float*)(smem + 8192);  // [16][128]
    if (fq == 0) {
#pragma unroll
        for (int j = 0; j < 8; ++j) {
            scrS[wave * 128 + j * 16 + frl] = ps[j];
            scrQ[wave * 128 + j * 16 + frl] = pq[j];
        }
    }
    __syncthreads();
    if (tid < 128) {
        float s = 0.f, q = 0.f;
#pragma unroll
        for (int w = 0; w < 16; ++w) { s += scrS[w * 128 + tid]; q += scrQ[w * 128 + tid]; }
        atomicAdd(&sums[nb * 128 + tid], s);
        atomicAdd(&sqs[nb * 128 + tid], q);
    }
}

// ---------------------------------------------------------------------------
// GEMM2 v6 (unchanged from R11): B-only LDS (~70 KB) -> 2 blocks/CU,
// 4 waves/SIMD. 8 waves x (16 rows x 128 cols), BM=128, grid 1024. A direct
// from y1 with BN1+relu fold in the load shadow; finalize1 inlined.
// ---------------------------------------------------------------------------
__global__ __launch_bounds__(512, 4) void gemm2_kernel(
    const ushort_t* __restrict__ y1, const ushort_t* __restrict__ w2b,
    const float* __restrict__ sums1, const float* __restrict__ sqs1,
    const float* __restrict__ g1, const float* __restrict__ b1,
    ushort_t* __restrict__ y2, float* __restrict__ sums, float* __restrict__ sqs)
{
    __shared__ __align__(16) char smem[69632];
    ushort_t* Bs = (ushort_t*)smem;                  // 128 x 264 = 67584 B
    float* sAv = (float*)(smem + 67584);             // 256 f
    float* sCv = (float*)(smem + 68608);             // 256 f
    const int tid = threadIdx.x;
    const int wave = tid >> 6, lane = tid & 63;
    const int frl = lane & 15, fq = lane >> 4;
    const int panel = blockIdx.x >> 1, nb = blockIdx.x & 1;
    const int m0 = panel * 128;

    if (tid < 256) {
        const float inv_n = 1.0f / 65536.0f;
        float mu = sums1[tid] * inv_n;
        float var = fmaf(-mu, mu, sqs1[tid] * inv_n);
        float is = 1.0f / sqrtf(var + 1e-5f);
        float aa = g1[tid] * is;
        sAv[tid] = aa;
        sCv[tid] = fmaf(-mu, aa, b1[tid]);
    }

    // stage B once: 4 threads per col, 8 x 8-elem chunks each
    {
        const int c = tid >> 2, qq = tid & 3;
        const ushort_t* src = w2b + (size_t)(nb * 128 + c) * 256;
        ushort_t* dst = Bs + c * 264;
#pragma unroll
        for (int s = 0; s < 8; ++s) {
            int off = qq * 8 + s * 32;
            *(ushort8*)(dst + off) = *(const ushort8*)(src + off);
        }
    }

    f32x4 acc[8];
#pragma unroll
    for (int j = 0; j < 8; ++j) acc[j] = f32x4{0.0f, 0.0f, 0.0f, 0.0f};

    const int row0 = m0 + wave * 16 + frl;   // fixed row per thread

    __syncthreads();   // coeffs + B visible; only barrier before K-loop

    bf16x8 afb[2], bfb[2][8];

#define G2_LOADA(buf, kc) {                                                        \
    ushort8 raw = *(const ushort8*)(y1 + (size_t)row0 * 256 + (kc) * 32 + fq * 8); \
    ushort8 hv;                                                                    \
    _Pragma("unroll")                                                              \
    for (int e = 0; e < 8; ++e) {                                                  \
        const int kk = (kc) * 32 + fq * 8 + e;                                     \
        float v = bf2f(raw[e]);                                                    \
        hv[e] = f2bf(fmaxf(fmaf(v, sAv[kk], sCv[kk]), 0.0f));                      \
    }                                                                              \
    buf = u2b(hv); }
#define G2_LOADB(buf, kc) { _Pragma("unroll")                                      \
    for (int j = 0; j < 8; ++j)                                                    \
        buf[j] = *(const bf16x8*)(Bs + (j * 16 + frl) * 264 + (kc) * 32 + fq * 8); }

    G2_LOADA(afb[0], 0); G2_LOADB(bfb[0], 0);
#pragma unroll
    for (int kc = 0; kc < 8; ++kc) {
        const int cur = kc & 1, nxt = cur ^ 1;
        if (kc < 7) { G2_LOADA(afb[nxt], kc + 1); G2_LOADB(bfb[nxt], kc + 1); }
#pragma unroll
        for (int j = 0; j < 8; ++j)
            acc[j] = __builtin_amdgcn_mfma_f32_16x16x32_bf16(afb[cur], bfb[cur][j], acc[j], 0, 0, 0);
    }

    // epilogue: y2 store + per-col stats
    float ps[8], pq[8];
#pragma unroll
    for (int j = 0; j < 8; ++j) {
        const int colg = nb * 128 + j * 16 + frl;
        float s = 0.f, q = 0.f;
#pragma unroll
        for (int rr = 0; rr < 4; ++rr) {
            ushort_t hb = f2bf(acc[j][rr]);
            float v = bf2f(hb);
            y2[(size_t)(m0 + wave * 16 + fq * 4 + rr) * 256 + colg] = hb;
            s += v; q = fmaf(v, v, q);
        }
        s += __shfl_xor(s, 16); s += __shfl_xor(s, 32);
        q += __shfl_xor(q, 16); q += __shfl_xor(q, 32);
        ps[j] = s; pq[j] = q;
    }
    __syncthreads();                      // Bs dead -> scratch (coeffs untouched)
    float* scrS = (float*)smem;           // [8][128]
    float* scrQ = (float*)(smem + 4096);  // [8][128]
    if (fq == 0) {
#pragma unroll
        for (int j = 0; j < 8; ++j) {
            scrS[wave * 128 + j * 16 + frl] = ps[j];
            scrQ[wave * 128 + j * 16 + frl] = pq[j];
        }
    }
    __syncthreads();
    if (tid < 128) {
        float s = 0.f, q = 0.f;
#pragma unroll
        for (int w = 0; w < 8; ++w) { s += scrS[w * 128 + tid]; q += scrQ[w * 128 + tid]; }
        atomicAdd(&sums[nb * 128 + tid], s);
        atomicAdd(&sqs[nb * 128 + tid], q);
    }
}

// ---------------------------------------------------------------------------
// apply v2: finalize2 INLINED. out(fp32) = relu(a2[c]*y2b + c2[c]).
// ---------------------------------------------------------------------------
__global__ __launch_bounds__(256) void apply_kernel(
    const ushort_t* __restrict__ y2,
    const float* __restrict__ sums2, const float* __restrict__ sqs2,
    const float* __restrict__ g2, const float* __restrict__ b2,
    float* __restrict__ out)
{
    __shared__ float sA[256], sC[256];
    {
        const int ch2 = threadIdx.x;
        const float inv_n = 1.0f / 65536.0f;
        float mu = sums2[ch2] * inv_n;
        float var = fmaf(-mu, mu, sqs2[ch2] * inv_n);
        float is = 1.0f / sqrtf(var + 1e-5f);
        float aa = g2[ch2] * is;
        sA[ch2] = aa;
        sC[ch2] = fmaf(-mu, aa, b2[ch2]);
    }
    __syncthreads();
    const size_t i = ((size_t)blockIdx.x * 256 + threadIdx.x) * 8;
    const int ch = (int)(i & 255);
    ushort8 raw = *(const ushort8*)(y2 + i);
    float4 o0, o1;
    const float4 a0 = *(const float4*)(sA + ch), a1v = *(const float4*)(sA + ch + 4);
    const float4 c0 = *(const float4*)(sC + ch), c1v = *(const float4*)(sC + ch + 4);
    o0.x = fmaxf(fmaf(bf2f(raw[0]), a0.x, c0.x), 0.0f);
    o0.y = fmaxf(fmaf(bf2f(raw[1]), a0.y, c0.y), 0.0f);
    o0.z = fmaxf(fmaf(bf2f(raw[2]), a0.z, c0.z), 0.0f);
    o0.w = fmaxf(fmaf(bf2f(raw[3]), a0.w, c0.w), 0.0f);
    o1.x = fmaxf(fmaf(bf2f(raw[4]), a1v.x, c1v.x), 0.0f);
    o1.y = fmaxf(fmaf(bf2f(raw[5]), a1v.y, c1v.y), 0.0f);
    o1.z = fmaxf(fmaf(bf2f(raw[6]), a1v.z, c1v.z), 0.0f);
    o1.w = fmaxf(fmaf(bf2f(raw[7]), a1v.w, c1v.w), 0.0f);
    *(float4*)(out + i) = o0;
    *(float4*)(out + i + 4) = o1;
}

extern "C" void kernel_launch(void* const* d_in, const int* in_sizes, int n_in,
                              void* d_out, int out_size, void* d_ws, size_t ws_size,
                              hipStream_t stream)
{
    const float* xyz1    = (const float*)d_in[0];
    const float* xyz2    = (const float*)d_in[1];
    const float* points1 = (const float*)d_in[2];
    const float* points2 = (const float*)d_in[3];
    const float* w1      = (const float*)d_in[4];
    const float* g1      = (const float*)d_in[5];
    const float* b1      = (const float*)d_in[6];
    const float* w2      = (const float*)d_in[7];
    const float* g2      = (const float*)d_in[8];
    const float* b2      = (const float*)d_in[9];
    float* out = (float*)d_out;

    char* ws = (char*)d_ws;
    float* sums1 = (float*)(ws + 0);
    float* sqs1  = (float*)(ws + 1024);
    float* sums2 = (float*)(ws + 4096);
    float* sqs2  = (float*)(ws + 5120);
    ushort_t* w1b = (ushort_t*)(ws + (64u << 10));    // 256 KB
    ushort_t* w2b = (ushort_t*)(ws + (320u << 10));   // 128 KB
    ushort_t* p2b = (ushort_t*)(ws + (1u << 20));     // 8.4 MB
    int*   idx   = (int*)(ws + (10u << 20));          // 768 KB
    float* wgt   = (float*)(ws + (11u << 20));        // 768 KB
    ushort_t* y2b = (ushort_t*)(ws + (12u << 20));    // 32 MB
    ushort_t* y1  = (ushort_t*)(ws + (44u << 20));    // 32 MB

    prep_kernel<<<dim3(4865), 256, 0, stream>>>(w1, w2, points2, w1b, w2b, p2b, (float*)ws);
    knn_kernel<<<dim3(128, 16), 256, 0, stream>>>(xyz1, xyz2, idx, wgt);
    gemm1_kernel<<<dim3(512), 1024, 0, stream>>>(points1, p2b, idx, wgt, w1b, y1, sums1, sqs1);
    gemm2_kernel<<<dim3(1024), 512, 0, stream>>>(y1, w2b, sums1, sqs1, g1, b1, y2b, sums2, sqs2);
    apply_kernel<<<dim3(8192), 256, 0, stream>>>(y2b, sums2, sqs2, g2, b2, out);
}

// Round 13
// 262.698 us; speedup vs baseline: 1.0834x; 1.0834x over previous
//
#include <hip/hip_runtime.h>
#include <stdint.h>

typedef unsigned short ushort_t;
typedef __bf16 bf16x8 __attribute__((ext_vector_type(8)));
typedef float f32x4 __attribute__((ext_vector_type(4)));
typedef unsigned short ushort8 __attribute__((ext_vector_type(8)));
typedef unsigned short ushort4_t __attribute__((ext_vector_type(4)));

#define DEV static __device__ __forceinline__

DEV unsigned short f2bf(float f) {
    union { float f; unsigned int i; } v; v.f = f;
    unsigned int u = v.i;
    return (unsigned short)((u + 0x7fffu + ((u >> 16) & 1u)) >> 16);
}
DEV float bf2f(unsigned short u) {
    union { unsigned int i; float f; } v; v.i = ((unsigned int)u) << 16; return v.f;
}
DEV bf16x8 u2b(ushort8 u) { union { ushort8 u; bf16x8 b; } x; x.u = u; return x.b; }

// ---------------------------------------------------------------------------
// prep: w1->bf16, w2->bf16, points2->bf16, zero BN stat accumulators.
// ---------------------------------------------------------------------------
__global__ __launch_bounds__(256) void prep_kernel(
    const float* __restrict__ w1, const float* __restrict__ w2,
    const float* __restrict__ points2,
    ushort_t* __restrict__ w1b, ushort_t* __restrict__ w2b,
    ushort_t* __restrict__ p2b, float* __restrict__ stats)
{
    const int bx = blockIdx.x;
    if (bx < 512) {
        int i = bx * 256 + threadIdx.x;
        w1b[i] = f2bf(w1[i]);
    } else if (bx < 768) {
        int i = (bx - 512) * 256 + threadIdx.x;
        w2b[i] = f2bf(w2[i]);
    } else if (bx < 4864) {
        int i = ((bx - 768) * 256 + threadIdx.x) * 4;
        float4 v = *(const float4*)(points2 + i);
        ushort4_t o;
        o[0] = f2bf(v.x); o[1] = f2bf(v.y); o[2] = f2bf(v.z); o[3] = f2bf(v.w);
        *(ushort4_t*)(p2b + i) = o;
    } else {
        int i = threadIdx.x * 8;
        *(float4*)(stats + i)     = make_float4(0.f, 0.f, 0.f, 0.f);
        *(float4*)(stats + i + 4) = make_float4(0.f, 0.f, 0.f, 0.f);
    }
}

// ---------------------------------------------------------------------------
// 3-NN: 8-way candidate split. Stable ties.
// ---------------------------------------------------------------------------
__global__ __launch_bounds__(256) void knn_kernel(
    const float* __restrict__ xyz1, const float* __restrict__ xyz2,
    int* __restrict__ idx_out, float* __restrict__ w_out)
{
    __shared__ float4 P[1024];
    __shared__ float mD[24][32];
    __shared__ int   mI[24][32];
    const int b = blockIdx.y;
    const int tid = threadIdx.x;
    for (int s = tid; s < 1024; s += 256) {
        const float* p = xyz2 + ((size_t)b * 1024 + s) * 3;
        float x = p[0], y = p[1], z = p[2];
        float pp = __fadd_rn(__fadd_rn(__fmul_rn(x, x), __fmul_rn(y, y)), __fmul_rn(z, z));
        P[s] = make_float4(x, y, z, pp);
    }
    __syncthreads();
    const int ql = tid & 31;
    const int chunk = tid >> 5;
    const int n = blockIdx.x * 32 + ql;
    const float* q = xyz1 + ((size_t)b * 4096 + n) * 3;
    float qx = q[0], qy = q[1], qz = q[2];
    float qq = __fadd_rn(__fadd_rn(__fmul_rn(qx, qx), __fmul_rn(qy, qy)), __fmul_rn(qz, qz));
    float d0 = 1e30f, d1 = 1e30f, d2 = 1e30f;
    int i0 = 0, i1 = 0, i2 = 0;
    const int s0 = chunk * 128;
#pragma unroll 4
    for (int s = s0; s < s0 + 128; ++s) {
        float4 p = P[s];
        float dot = __fadd_rn(__fadd_rn(__fmul_rn(qx, p.x), __fmul_rn(qy, p.y)), __fmul_rn(qz, p.z));
        float d = __fsub_rn(__fadd_rn(qq, p.w), __fmul_rn(2.0f, dot));
        if (d < d2) {
            if (d < d1) {
                d2 = d1; i2 = i1;
                if (d < d0) { d1 = d0; i1 = i0; d0 = d; i0 = s; }
                else        { d1 = d;  i1 = s; }
            } else { d2 = d; i2 = s; }
        }
    }
    mD[chunk * 3 + 0][ql] = d0; mI[chunk * 3 + 0][ql] = i0;
    mD[chunk * 3 + 1][ql] = d1; mI[chunk * 3 + 1][ql] = i1;
    mD[chunk * 3 + 2][ql] = d2; mI[chunk * 3 + 2][ql] = i2;
    __syncthreads();
    if (tid < 32) {
        float e0 = 1e30f, e1 = 1e30f, e2 = 1e30f;
        int j0 = 0, j1 = 0, j2 = 0;
#pragma unroll
        for (int c = 0; c < 24; ++c) {
            float d = mD[c][ql]; int i = mI[c][ql];
            if (d < e2) {
                if (d < e1) {
                    e2 = e1; j2 = j1;
                    if (d < e0) { e1 = e0; j1 = j0; e0 = d; j0 = i; }
                    else        { e1 = d;  j1 = i; }
                } else { e2 = d; j2 = i; }
            }
        }
        float r0 = 1.0f / (e0 + 1e-8f);
        float r1 = 1.0f / (e1 + 1e-8f);
        float r2 = 1.0f / (e2 + 1e-8f);
        float rs = __fadd_rn(__fadd_rn(r0, r1), r2);
        size_t o = ((size_t)b * 4096 + n) * 3;
        idx_out[o + 0] = j0; idx_out[o + 1] = j1; idx_out[o + 2] = j2;
        w_out[o + 0] = r0 / rs; w_out[o + 1] = r1 / rs; w_out[o + 2] = r2 / rs;
    }
}

DEV void cvt8(const float4& u0, const float4& u1, ushort8& hv) {
    hv[0] = f2bf(u0.x); hv[1] = f2bf(u0.y); hv[2] = f2bf(u0.z); hv[3] = f2bf(u0.w);
    hv[4] = f2bf(u1.x); hv[5] = f2bf(u1.y); hv[6] = f2bf(u1.z); hv[7] = f2bf(u1.w);
}

// ---------------------------------------------------------------------------
// GEMM1 v11 EXACT (best measured: 67us, FETCH 41MB, WRITE 35MB, no spill).
// Interp fused in-loop + batch-affine XCD swizzle. 16-wave block, wave =
// 16 rows x 128 cols, BM=256, BN=128, barrier-free K-loop, 2-deep reg dbuf,
// B double-buffered from 133 KB LDS. Register frontier: v12 (full-unroll
// aPre hoist, +32 live) and v13 (single-buf B + unrolled prologue bulk
// loads) BOTH spilled (WRITE 142/111 MB). Do not add register state without
// pinning prologue unroll.
// ---------------------------------------------------------------------------
__global__ __launch_bounds__(1024, 4) void gemm1_kernel(
    const float* __restrict__ p1, const ushort_t* __restrict__ p2b,
    const int* __restrict__ idx, const float* __restrict__ wgt,
    const ushort_t* __restrict__ w1b, ushort_t* __restrict__ y,
    float* __restrict__ sums, float* __restrict__ sqs)
{
    __shared__ __align__(16) char smem[133120];   // Bs: 128 x 520 ushort
    ushort_t* Bs = (ushort_t*)smem;
    const int tid = threadIdx.x;
    const int wave = tid >> 6, lane = tid & 63;
    const int frl = lane & 15, fq = lane >> 4;
    // batch-affine XCD swizzle: bid -> (panel, nb)
    const int bid = blockIdx.x;
    const int xcd = bid & 7;
    const int j6 = bid >> 3;                 // 0..63
    const int batch = xcd * 2 + (j6 >> 5);   // 0..15
    const int wblk = j6 & 31;                // 0..31 within batch
    const int panel = batch * 16 + (wblk >> 1), nb = wblk & 1;
    const int m0 = panel * 256;

    // stage B once: 8 threads per col, 8 x 8-elem chunks each
    {
        const int c = tid >> 3, qq = tid & 7;
        const ushort_t* src = w1b + (size_t)(nb * 128 + c) * 512;
        ushort_t* dst = Bs + c * 520;
#pragma unroll
        for (int s = 0; s < 8; ++s) {
            int off = qq * 8 + s * 64;
            *(ushort8*)(dst + off) = *(const ushort8*)(src + off);
        }
    }

    f32x4 acc[8];
#pragma unroll
    for (int j = 0; j < 8; ++j) acc[j] = f32x4{0.0f, 0.0f, 0.0f, 0.0f};

    const int row0 = m0 + wave * 16 + frl;   // fixed row per thread
    // prologue: 3-NN indices/weights + gather bases for this row (once)
    const size_t io = (size_t)row0 * 3;
    const float iw0 = wgt[io], iw1 = wgt[io + 1], iw2 = wgt[io + 2];
    const ushort_t* pb = p2b + (size_t)(row0 >> 12) * (1024 * 256);
    const ushort_t* gp0 = pb + (size_t)idx[io] * 256 + fq * 8;
    const ushort_t* gp1 = pb + (size_t)idx[io + 1] * 256 + fq * 8;
    const ushort_t* gp2 = pb + (size_t)idx[io + 2] * 256 + fq * 8;

    __syncthreads();   // only barrier before K-loop

    bf16x8 afb[2], bfb[2][8];

#define G1_LOADA(buf, kc) {                                                        \
    if ((kc) < 8) {                                                                \
        const float4* g = (const float4*)(p1 + (size_t)row0 * 256                  \
                                          + (kc) * 32 + fq * 8);                   \
        float4 u0 = g[0], u1 = g[1];                                               \
        ushort8 hv; cvt8(u0, u1, hv);                                              \
        buf = u2b(hv);                                                             \
    } else {                                                                       \
        ushort8 ga = *(const ushort8*)(gp0 + ((kc) - 8) * 32);                     \
        ushort8 gb = *(const ushort8*)(gp1 + ((kc) - 8) * 32);                     \
        ushort8 gc = *(const ushort8*)(gp2 + ((kc) - 8) * 32);                     \
        ushort8 hv;                                                                \
        _Pragma("unroll")                                                          \
        for (int e = 0; e < 8; ++e) {                                              \
            float av = __fmul_rn(iw0, bf2f(ga[e]));                                \
            av = fmaf(iw1, bf2f(gb[e]), av);                                       \
            av = fmaf(iw2, bf2f(gc[e]), av);                                       \
            hv[e] = f2bf(av);                                                      \
        }                                                                          \
        buf = u2b(hv);                                                             \
    } }
#define G1_LOADB(buf, kc) { _Pragma("unroll")                                      \
    for (int j = 0; j < 8; ++j)                                                    \
        buf[j] = *(const bf16x8*)(Bs + (j * 16 + frl) * 520 + (kc) * 32 + fq * 8); }

    G1_LOADA(afb[0], 0); G1_LOADB(bfb[0], 0);
#pragma unroll
    for (int kc = 0; kc < 16; ++kc) {
        const int cur = kc & 1, nxt = cur ^ 1;
        if (kc < 15) { G1_LOADA(afb[nxt], kc + 1); G1_LOADB(bfb[nxt], kc + 1); }
#pragma unroll
        for (int j = 0; j < 8; ++j)
            acc[j] = __builtin_amdgcn_mfma_f32_16x16x32_bf16(afb[cur], bfb[cur][j], acc[j], 0, 0, 0);
    }

    // epilogue: y1 store + per-col stats
    float ps[8], pq[8];
#pragma unroll
    for (int j = 0; j < 8; ++j) {
        const int colg = nb * 128 + j * 16 + frl;
        float s = 0.f, q = 0.f;
#pragma unroll
        for (int rr = 0; rr < 4; ++rr) {
            ushort_t hb = f2bf(acc[j][rr]);
            float v = bf2f(hb);
            y[(size_t)(m0 + wave * 16 + fq * 4 + rr) * 256 + colg] = hb;
            s += v; q = fmaf(v, v, q);
        }
        s += __shfl_xor(s, 16); s += __shfl_xor(s, 32);
        q += __shfl_xor(q, 16); q += __shfl_xor(q, 32);
        ps[j] = s; pq[j] = q;
    }
    __syncthreads();                      // Bs now dead -> reuse as scratch
    float* scrS = (float*)smem;           // [16][128]
    float* scrQ = (float*)(smem + 8192);  // [16][128]
    if (fq == 0) {
#pragma unroll
        for (int j = 0; j < 8; ++j) {
            scrS[wave * 128 + j * 16 + frl] = ps[j];
            scrQ[wave * 128 + j * 16 + frl] = pq[j];
        }
    }
    __syncthreads();
    if (tid < 128) {
        float s = 0.f, q = 0.f;
#pragma unroll
        for (int w = 0; w < 16; ++w) { s += scrS[w * 128 + tid]; q += scrQ[w * 128 + tid]; }
        atomicAdd(&sums[nb * 128 + tid], s);
        atomicAdd(&sqs[nb * 128 + tid], q);
    }
}

// ---------------------------------------------------------------------------
// GEMM2 v7 = v6 + batch-affine XCD swizzle (same lever that cut gemm1's
// FETCH 112->41 MB). Grid 1024 = 16 batches x 32 panels x 2 N-halves; decode
// puts each batch's 64 blocks (incl. both twins of every panel) on ONE XCD,
// so the twin y1 re-read and w2b hit that XCD's L2. Bijective (1024%8==0).
// Rest unchanged: B-only LDS (~70 KB) -> 2 blocks/CU, 4 waves/SIMD; 8 waves
// x (16 rows x 128 cols), BM=128; A direct from y1 with BN1+relu fold in the
// load shadow; finalize1 inlined.
// ---------------------------------------------------------------------------
__global__ __launch_bounds__(512, 4) void gemm2_kernel(
    const ushort_t* __restrict__ y1, const ushort_t* __restrict__ w2b,
    const float* __restrict__ sums1, const float* __restrict__ sqs1,
    const float* __restrict__ g1, const float* __restrict__ b1,
    ushort_t* __restrict__ y2, float* __restrict__ sums, float* __restrict__ sqs)
{
    __shared__ __align__(16) char smem[69632];
    ushort_t* Bs = (ushort_t*)smem;                  // 128 x 264 = 67584 B
    float* sAv = (float*)(smem + 67584);             // 256 f
    float* sCv = (float*)(smem + 68608);             // 256 f
    const int tid = threadIdx.x;
    const int wave = tid >> 6, lane = tid & 63;
    const int frl = lane & 15, fq = lane >> 4;
    // batch-affine XCD swizzle: bid -> (panel, nb)
    const int bid = blockIdx.x;
    const int xcd = bid & 7;
    const int j7 = bid >> 3;                  // 0..127
    const int batch = xcd * 2 + (j7 >> 6);    // 0..15
    const int within = j7 & 63;               // 0..63 = 32 panels x 2 halves
    const int panel = batch * 32 + (within >> 1), nb = within & 1;
    const int m0 = panel * 128;

    if (tid < 256) {
        const float inv_n = 1.0f / 65536.0f;
        float mu = sums1[tid] * inv_n;
        float var = fmaf(-mu, mu, sqs1[tid] * inv_n);
        float is = 1.0f / sqrtf(var + 1e-5f);
        float aa = g1[tid] * is;
        sAv[tid] = aa;
        sCv[tid] = fmaf(-mu, aa, b1[tid]);
    }

    // stage B once: 4 threads per col, 8 x 8-elem chunks each
    {
        const int c = tid >> 2, qq = tid & 3;
        const ushort_t* src = w2b + (size_t)(nb * 128 + c) * 256;
        ushort_t* dst = Bs + c * 264;
#pragma unroll
        for (int s = 0; s < 8; ++s) {
            int off = qq * 8 + s * 32;
            *(ushort8*)(dst + off) = *(const ushort8*)(src + off);
        }
    }

    f32x4 acc[8];
#pragma unroll
    for (int j = 0; j < 8; ++j) acc[j] = f32x4{0.0f, 0.0f, 0.0f, 0.0f};

    const int row0 = m0 + wave * 16 + frl;   // fixed row per thread

    __syncthreads();   // coeffs + B visible; only barrier before K-loop

    bf16x8 afb[2], bfb[2][8];

#define G2_LOADA(buf, kc) {                                                        \
    ushort8 raw = *(const ushort8*)(y1 + (size_t)row0 * 256 + (kc) * 32 + fq * 8); \
    ushort8 hv;                                                                    \
    _Pragma("unroll")                                                              \
    for (int e = 0; e < 8; ++e) {                                                  \
        const int kk = (kc) * 32 + fq * 8 + e;                                     \
        float v = bf2f(raw[e]);                                                    \
        hv[e] = f2bf(fmaxf(fmaf(v, sAv[kk], sCv[kk]), 0.0f));                      \
    }                                                                              \
    buf = u2b(hv); }
#define G2_LOADB(buf, kc) { _Pragma("unroll")                                      \
    for (int j = 0; j < 8; ++j)                                                    \
        buf[j] = *(const bf16x8*)(Bs + (j * 16 + frl) * 264 + (kc) * 32 + fq * 8); }

    G2_LOADA(afb[0], 0); G2_LOADB(bfb[0], 0);
#pragma unroll
    for (int kc = 0; kc < 8; ++kc) {
        const int cur = kc & 1, nxt = cur ^ 1;
        if (kc < 7) { G2_LOADA(afb[nxt], kc + 1); G2_LOADB(bfb[nxt], kc + 1); }
#pragma unroll
        for (int j = 0; j < 8; ++j)
            acc[j] = __builtin_amdgcn_mfma_f32_16x16x32_bf16(afb[cur], bfb[cur][j], acc[j], 0, 0, 0);
    }

    // epilogue: y2 store + per-col stats
    float ps[8], pq[8];
#pragma unroll
    for (int j = 0; j < 8; ++j) {
        const int colg = nb * 128 + j * 16 + frl;
        float s = 0.f, q = 0.f;
#pragma unroll
        for (int rr = 0; rr < 4; ++rr) {
            ushort_t hb = f2bf(acc[j][rr]);
            float v = bf2f(hb);
            y2[(size_t)(m0 + wave * 16 + fq * 4 + rr) * 256 + colg] = hb;
            s += v; q = fmaf(v, v, q);
        }
        s += __shfl_xor(s, 16); s += __shfl_xor(s, 32);
        q += __shfl_xor(q, 16); q += __shfl_xor(q, 32);
        ps[j] = s; pq[j] = q;
    }
    __syncthreads();                      // Bs dead -> scratch (coeffs untouched)
    float* scrS = (float*)smem;           // [8][128]
    float* scrQ = (float*)(smem + 4096);  // [8][128]
    if (fq == 0) {
#pragma unroll
        for (int j = 0; j < 8; ++j) {
            scrS[wave * 128 + j * 16 + frl] = ps[j];
            scrQ[wave * 128 + j * 16 + frl] = pq[j];
        }
    }
    __syncthreads();
    if (tid < 128) {
        float s = 0.f, q = 0.f;
#pragma unroll
        for (int w = 0; w < 8; ++w) { s += scrS[w * 128 + tid]; q += scrQ[w * 128 + tid]; }
        atomicAdd(&sums[nb * 128 + tid], s);
        atomicAdd(&sqs[nb * 128 + tid], q);
    }
}

// ---------------------------------------------------------------------------
// apply v2: finalize2 INLINED. out(fp32) = relu(a2[c]*y2b + c2[c]).
// ---------------------------------------------------------------------------
__global__ __launch_bounds__(256) void apply_kernel(
    const ushort_t* __restrict__ y2,
    const float* __restrict__ sums2, const float* __restrict__ sqs2,
    const float* __restrict__ g2, const float* __restrict__ b2,
    float* __restrict__ out)
{
    __shared__ float sA[256], sC[256];
    {
        const int ch2 = threadIdx.x;
        const float inv_n = 1.0f / 65536.0f;
        float mu = sums2[ch2] * inv_n;
        float var = fmaf(-mu, mu, sqs2[ch2] * inv_n);
        float is = 1.0f / sqrtf(var + 1e-5f);
        float aa = g2[ch2] * is;
        sA[ch2] = aa;
        sC[ch2] = fmaf(-mu, aa, b2[ch2]);
    }
    __syncthreads();
    const size_t i = ((size_t)blockIdx.x * 256 + threadIdx.x) * 8;
    const int ch = (int)(i & 255);
    ushort8 raw = *(const ushort8*)(y2 + i);
    float4 o0, o1;
    const float4 a0 = *(const float4*)(sA + ch), a1v = *(const float4*)(sA + ch + 4);
    const float4 c0 = *(const float4*)(sC + ch), c1v = *(const float4*)(sC + ch + 4);
    o0.x = fmaxf(fmaf(bf2f(raw[0]), a0.x, c0.x), 0.0f);
    o0.y = fmaxf(fmaf(bf2f(raw[1]), a0.y, c0.y), 0.0f);
    o0.z = fmaxf(fmaf(bf2f(raw[2]), a0.z, c0.z), 0.0f);
    o0.w = fmaxf(fmaf(bf2f(raw[3]), a0.w, c0.w), 0.0f);
    o1.x = fmaxf(fmaf(bf2f(raw[4]), a1v.x, c1v.x), 0.0f);
    o1.y = fmaxf(fmaf(bf2f(raw[5]), a1v.y, c1v.y), 0.0f);
    o1.z = fmaxf(fmaf(bf2f(raw[6]), a1v.z, c1v.z), 0.0f);
    o1.w = fmaxf(fmaf(bf2f(raw[7]), a1v.w, c1v.w), 0.0f);
    *(float4*)(out + i) = o0;
    *(float4*)(out + i + 4) = o1;
}

extern "C" void kernel_launch(void* const* d_in, const int* in_sizes, int n_in,
                              void* d_out, int out_size, void* d_ws, size_t ws_size,
                              hipStream_t stream)
{
    const float* xyz1    = (const float*)d_in[0];
    const float* xyz2    = (const float*)d_in[1];
    const float* points1 = (const float*)d_in[2];
    const float* points2 = (const float*)d_in[3];
    const float* w1      = (const float*)d_in[4];
    const float* g1      = (const float*)d_in[5];
    const float* b1      = (const float*)d_in[6];
    const float* w2      = (const float*)d_in[7];
    const float* g2      = (const float*)d_in[8];
    const float* b2      = (const float*)d_in[9];
    float* out = (float*)d_out;

    char* ws = (char*)d_ws;
    float* sums1 = (float*)(ws + 0);
    float* sqs1  = (float*)(ws + 1024);
    float* sums2 = (float*)(ws + 4096);
    float* sqs2  = (float*)(ws + 5120);
    ushort_t* w1b = (ushort_t*)(ws + (64u << 10));    // 256 KB
    ushort_t* w2b = (ushort_t*)(ws + (320u << 10));   // 128 KB
    ushort_t* p2b = (ushort_t*)(ws + (1u << 20));     // 8.4 MB
    int*   idx   = (int*)(ws + (10u << 20));          // 768 KB
    float* wgt   = (float*)(ws + (11u << 20));        // 768 KB
    ushort_t* y2b = (ushort_t*)(ws + (12u << 20));    // 32 MB
    ushort_t* y1  = (ushort_t*)(ws + (44u << 20));    // 32 MB

    prep_kernel<<<dim3(4865), 256, 0, stream>>>(w1, w2, points2, w1b, w2b, p2b, (float*)ws);
    knn_kernel<<<dim3(128, 16), 256, 0, stream>>>(xyz1, xyz2, idx, wgt);
    gemm1_kernel<<<dim3(512), 1024, 0, stream>>>(points1, p2b, idx, wgt, w1b, y1, sums1, sqs1);
    gemm2_kernel<<<dim3(1024), 512, 0, stream>>>(y1, w2b, sums1, sqs1, g1, b1, y2b, sums2, sqs2);
    apply_kernel<<<dim3(8192), 256, 0, stream>>>(y2b, sums2, sqs2, g2, b2, out);
}